// Round 3
// baseline (496.857 us; speedup 1.0000x reference)
//
#include <hip/hip_runtime.h>
#include <hip/hip_bf16.h>

// Shapes (fixed): B=32, S=2048, E=1024, U=1024. M = B*S = 65536.
// score[m] = v . tanh( lhs[m,:] @ (W+U)^T )  -- 256x256/BK=64 8-phase MFMA GEMM
//   (T2 both-sides XOR swizzle + T3/T4 counted vmcnt(4) + T5 setprio)
//   Race-free stage schedule: each half staged the phase AFTER its last read.
// out[b,:] = sum_s softmax(score)[s] * row[s]  -- fused softmax+wsum (compact order)
//
// ws: (2MB unused) | wsumrm bf16 [2MB,4MB) | score [4MB,+256KB) | alphac [+256KB)
//     | ridx u16 [4.5MB,+128KB) | cnt i32 [4.625MB,+128B) | Ab bf16 [5MB,+128MB)

typedef short bf16x8 __attribute__((ext_vector_type(8)));
typedef float f32x4  __attribute__((ext_vector_type(4)));
typedef unsigned short u16x8 __attribute__((ext_vector_type(8)));

static __device__ __forceinline__ unsigned short f2bf(float f) {
    unsigned int x = __float_as_uint(f);
    unsigned int r = x + 0x7FFFu + ((x >> 16) & 1u);   // RNE
    return (unsigned short)(r >> 16);
}

static __device__ __forceinline__ float fast_tanh(float x) {
    float e = __builtin_amdgcn_exp2f(x * 2.885390082f);   // e^{2x}
    float r = __builtin_amdgcn_rcpf(e + 1.0f);
    return __builtin_fmaf(-2.0f, r, 1.0f);
}

// ---------------- K0: [0..1023] wsumrm = bf16(W+U) row-major, zero score/out
//                      [1024..1055] per-batch valid-row index scan ----------------
__global__ __launch_bounds__(256)
void prep_index(const float* __restrict__ W, const float* __restrict__ U,
                const int* __restrict__ mask,
                unsigned short* __restrict__ wsumrm,
                float* __restrict__ score, float* __restrict__ out,
                unsigned short* __restrict__ ridx, int* __restrict__ cnt) {
    __shared__ int sc[256];
    int blk = blockIdx.x, t = threadIdx.x;
    if (blk < 1024) {
        int g = blk * 256 + t;
        int i4 = g * 4;                       // 4 consecutive k of row n
        float4 w = *(const float4*)&W[i4];
        float4 u = *(const float4*)&U[i4];
        ushort4 h;
        h.x = f2bf(w.x + u.x); h.y = f2bf(w.y + u.y);
        h.z = f2bf(w.z + u.z); h.w = f2bf(w.w + u.w);
        *(ushort4*)&wsumrm[i4] = h;           // row-major [n][k]
        if (g < 65536) score[g] = 0.0f;
        if (g < 32768) out[g] = 0.0f;
    } else {
        int b = blk - 1024;
        const int* mrow = mask + b * 2048;
        int m[8], c = 0;
#pragma unroll
        for (int j = 0; j < 8; ++j) { m[j] = mrow[t * 8 + j]; c += (m[j] != 0); }
        sc[t] = c;
        __syncthreads();
        for (int off = 1; off < 256; off <<= 1) {
            int v = (t >= off) ? sc[t - off] : 0;
            __syncthreads();
            sc[t] += v;
            __syncthreads();
        }
        int base = sc[t] - c;
        unsigned short* rb = ridx + b * 2048;
#pragma unroll
        for (int j = 0; j < 8; ++j)
            if (m[j]) rb[base++] = (unsigned short)(t * 8 + j);
        if (t == 255) cnt[b] = sc[255];
    }
}

// ---------------- K1: gather valid rows -> bf16 compact (zero-pad to x256) ----------------
__global__ __launch_bounds__(256)
void gather_convert(const float* __restrict__ lhs, const unsigned short* __restrict__ ridx,
                    const int* __restrict__ cnt, unsigned short* __restrict__ Ab) {
    int b = blockIdx.y;
    int c = cnt[b];
    int cpad = (c + 255) & ~255;
    int r = blockIdx.x * 4 + (threadIdx.x >> 6);
    int lt = threadIdx.x & 63;
    if (r >= cpad) return;
    unsigned short* dst = Ab + ((size_t)b * 2048 + r) * 1024 + lt * 16;
    if (r < c) {
        int s = ridx[b * 2048 + r];
        const float* src = lhs + ((size_t)b * 2048 + s) * 1024 + lt * 16;
        float4 a0 = *(const float4*)(src + 0);
        float4 a1 = *(const float4*)(src + 4);
        float4 a2 = *(const float4*)(src + 8);
        float4 a3 = *(const float4*)(src + 12);
        u16x8 h0, h1;
        h0[0] = f2bf(a0.x); h0[1] = f2bf(a0.y); h0[2] = f2bf(a0.z); h0[3] = f2bf(a0.w);
        h0[4] = f2bf(a1.x); h0[5] = f2bf(a1.y); h0[6] = f2bf(a1.z); h0[7] = f2bf(a1.w);
        h1[0] = f2bf(a2.x); h1[1] = f2bf(a2.y); h1[2] = f2bf(a2.z); h1[3] = f2bf(a2.w);
        h1[4] = f2bf(a3.x); h1[5] = f2bf(a3.y); h1[6] = f2bf(a3.z); h1[7] = f2bf(a3.w);
        *(u16x8*)(dst + 0) = h0;
        *(u16x8*)(dst + 8) = h1;
    } else {
        u16x8 z = (u16x8){0,0,0,0,0,0,0,0};
        *(u16x8*)(dst + 0) = z;
        *(u16x8*)(dst + 8) = z;
    }
}

// ---------------- K2: score GEMM -- 256x256 tile, BK=64, 8 waves (2Mx4N), 8-phase ---------
// LDS (128 KiB): A[buf][half][128x64 bf16] at buf*16384+half*8192 shorts (16 KiB each),
//                B same at +32768 shorts. Half-tile staged = 2 x global_load_lds(16B)/thread.
// Staging slot s=j*512+t covers row lr=s>>3, 16B-slot s&7; SOURCE k-slot pre-swizzled:
//   ks = (s&7) ^ (lr&7)  =>  LDS[lr][slot] = A[lr][slot ^ (lr&7)]  (T2 both-sides).
// Wave wv: wm=wv>>2 (M), wn=wv&3 (N). Phase (mq,nq) uses exactly A-half mq + B-half nq.
// Last-read phases: A0:p1  B0:p2  A1:p3  B1:p3.  RACE-FREE stage map (stage strictly
// after last read, >=1 barrier apart):
//   p0 -> A1(bufn,kt+1)   p1 -> B1(bufn,kt+1)   p2 -> A0(buf,kt+2)   p3 -> B0(buf,kt+2)
// vmcnt(4) only at p3: retires all 8 loads of kt+1; A0/B0 of kt+2 stay in flight.
#define GLD(SRC, LOFF) __builtin_amdgcn_global_load_lds( \
    (const __attribute__((address_space(1))) unsigned int*)(SRC), \
    (__attribute__((address_space(3))) unsigned int*)&L[LOFF], 16, 0, 0)

#define STAGE_A(BUF, MQ, KT) do { \
    GLD(gA[MQ][0] + (KT) * 64, ((BUF) << 14) + ((MQ) << 13) + (wv << 9)); \
    GLD(gA[MQ][1] + (KT) * 64, ((BUF) << 14) + ((MQ) << 13) + 4096 + (wv << 9)); \
} while (0)

#define STAGE_B(BUF, NQ, KT) do { \
    GLD(gB[NQ][0] + (KT) * 64, 32768 + ((BUF) << 14) + ((NQ) << 13) + (wv << 9)); \
    GLD(gB[NQ][1] + (KT) * 64, 32768 + ((BUF) << 14) + ((NQ) << 13) + 4096 + (wv << 9)); \
} while (0)

#define VM4 asm volatile("s_waitcnt vmcnt(4)" ::: "memory");
#define VM0 asm volatile("s_waitcnt vmcnt(0)" ::: "memory");
#define VMNONE
#define NOSTAGE

#define PHASE(MQ, NQ, STAGES, VMW) do { \
    bf16x8 af[4][2]; bf16x8 bfr[2][2]; \
    const int ab_ = (buf << 14) + ((MQ) << 13) + arow_; \
    const int bb_ = 32768 + (buf << 14) + ((NQ) << 13) + brow_; \
    _Pragma("unroll") for (int i_ = 0; i_ < 4; ++i_) { \
        af[i_][0] = *(const bf16x8*)&L[ab_ + i_ * 1024 + koff0]; \
        af[i_][1] = *(const bf16x8*)&L[ab_ + i_ * 1024 + koff1]; \
    } \
    _Pragma("unroll") for (int j_ = 0; j_ < 2; ++j_) { \
        bfr[j_][0] = *(const bf16x8*)&L[bb_ + j_ * 1024 + koff0]; \
        bfr[j_][1] = *(const bf16x8*)&L[bb_ + j_ * 1024 + koff1]; \
    } \
    __builtin_amdgcn_sched_barrier(0); \
    STAGES \
    VMW \
    asm volatile("s_waitcnt lgkmcnt(8)" ::: "memory"); \
    __builtin_amdgcn_s_barrier(); \
    asm volatile("s_waitcnt lgkmcnt(0)" ::: "memory"); \
    __builtin_amdgcn_sched_barrier(0); \
    __builtin_amdgcn_s_setprio(1); \
    _Pragma("unroll") for (int i_ = 0; i_ < 4; ++i_) \
    _Pragma("unroll") for (int j_ = 0; j_ < 2; ++j_) { \
        acc[MQ][NQ][i_][j_] = __builtin_amdgcn_mfma_f32_16x16x32_bf16(af[i_][0], bfr[j_][0], acc[MQ][NQ][i_][j_], 0, 0, 0); \
        acc[MQ][NQ][i_][j_] = __builtin_amdgcn_mfma_f32_16x16x32_bf16(af[i_][1], bfr[j_][1], acc[MQ][NQ][i_][j_], 0, 0, 0); \
    } \
    __builtin_amdgcn_s_setprio(0); \
    __builtin_amdgcn_s_barrier(); \
    __builtin_amdgcn_sched_barrier(0); \
} while (0)

__global__ __launch_bounds__(512, 2)
void score_gemm_v4(const unsigned short* __restrict__ Ab,
                   const unsigned short* __restrict__ Bw,   // wsumrm [1024][1024]
                   const float* __restrict__ v, const int* __restrict__ cnt,
                   float* __restrict__ score) {
    __shared__ __align__(16) unsigned short L[65536];       // 128 KiB

    // bijective XCD swizzle: XCD x gets mt in [x*32,(x+1)*32), with all 4 n-blocks of an
    // m-tile consecutive on the same XCD (A-panel L2 reuse x4; B=2MB L2-resident).
    const int bid = (int)blockIdx.x;
    const int li  = (bid & 7) * 128 + (bid >> 3);
    const int mt  = li >> 2;                  // 0..255 (32 batches x 8 m-tiles)
    const int nI  = li & 3;                   // 0..3
    const int b   = mt >> 3;
    const int lm0 = (mt & 7) << 8;
    const int c   = cnt[b];
    if (lm0 >= ((c + 255) & ~255)) return;
    const int m0  = (b << 11) + lm0;
    const int n0  = nI << 8;

    const int t    = (int)threadIdx.x;
    const int lane = t & 63;
    const int wv   = t >> 6;                  // 0..7
    const int wm   = wv >> 2;                 // 0..1  (M)
    const int wn   = wv & 3;                  // 0..3  (N)
    const int ml   = lane & 15;
    const int q    = lane >> 4;

    // staging source pointers (pre-swizzled k-slot): slot s=j*512+t, lr=s>>3, ks=(t&7)^(lr&7)
    const int lr0 = t >> 3;
    const int ks  = (t & 7) ^ (lr0 & 7);
    const unsigned short* gA[2][2];
    const unsigned short* gB[2][2];
#pragma unroll
    for (int h = 0; h < 2; ++h)
#pragma unroll
        for (int j = 0; j < 2; ++j) {
            gA[h][j] = Ab + (size_t)(m0 + h * 128 + lr0 + j * 64) * 1024 + ks * 8;
            gB[h][j] = Bw + (size_t)(n0 + h * 128 + lr0 + j * 64) * 1024 + ks * 8;
        }

    // ds_read offsets (shorts): row*64 + ((ksub*64 + q*16) ^ ((row&7)<<4))>>1, row&7 == ml&7
    const int xorv  = (ml & 7) << 4;
    const int koff0 = (((q << 4)) ^ xorv) >> 1;
    const int koff1 = ((64 + (q << 4)) ^ xorv) >> 1;
    const int arow_ = ((wm << 6) + ml) * 64;
    const int brow_ = ((wn << 5) + ml) * 64;

    f32x4 acc[2][2][4][2];
#pragma unroll
    for (int x0 = 0; x0 < 2; ++x0)
#pragma unroll
        for (int x1 = 0; x1 < 2; ++x1)
#pragma unroll
            for (int x2 = 0; x2 < 4; ++x2)
#pragma unroll
                for (int x3 = 0; x3 < 2; ++x3)
                    acc[x0][x1][x2][x3] = (f32x4){0.f, 0.f, 0.f, 0.f};

    // prologue: kt0 {A0,B0,A1,B1} + kt1 {A0,B0}; vmcnt(4) retires all of kt0,
    // leaving A0/B0 of kt1 in flight == steady state entering the loop.
    STAGE_A(0, 0, 0); STAGE_B(0, 0, 0); STAGE_A(0, 1, 0); STAGE_B(0, 1, 0);
    STAGE_A(1, 0, 1); STAGE_B(1, 0, 1);
    VM4
    __builtin_amdgcn_s_barrier();

    for (int kt = 0; kt < 14; ++kt) {
        const int buf  = kt & 1;
        const int bufn = buf ^ 1;
        PHASE(0, 0, STAGE_A(bufn, 1, kt + 1);, VMNONE);   // A1 last read @p3 of kt-1
        PHASE(0, 1, STAGE_B(bufn, 1, kt + 1);, VMNONE);   // B1 last read @p3 of kt-1
        PHASE(1, 0, STAGE_A(buf, 0, kt + 2);,  VMNONE);   // A0 last read @p1 of kt
        PHASE(1, 1, STAGE_B(buf, 0, kt + 2);,  VM4);      // B0 last read @p2; retire kt+1
    }
    {   // kt = 14 (buf 0): only A1/B1 of kt15 left to stage; drain fully before last tile
        const int buf = 0;
        PHASE(0, 0, STAGE_A(1, 1, 15);, VMNONE);
        PHASE(0, 1, STAGE_B(1, 1, 15);, VMNONE);
        PHASE(1, 0, NOSTAGE;, VMNONE);
        PHASE(1, 1, NOSTAGE;, VM0);
    }
    {   // kt = 15 (buf 1): pure compute
        const int buf = 1;
        PHASE(0, 0, NOSTAGE;, VMNONE);
        PHASE(0, 1, NOSTAGE;, VMNONE);
        PHASE(1, 0, NOSTAGE;, VMNONE);
        PHASE(1, 1, NOSTAGE;, VMNONE);
    }

    // epilogue: score[m] += sum_n v[n]*tanh(P[m,n]).  D layout: col=ml (n), row=q*4+r (m).
    float vw[2][2];
#pragma unroll
    for (int nq = 0; nq < 2; ++nq)
#pragma unroll
        for (int j = 0; j < 2; ++j)
            vw[nq][j] = v[n0 + nq * 128 + (wn << 5) + j * 16 + ml];

#pragma unroll
    for (int mq = 0; mq < 2; ++mq)
#pragma unroll
        for (int i = 0; i < 4; ++i)
#pragma unroll
            for (int r = 0; r < 4; ++r) {
                float val = fast_tanh(acc[mq][0][i][0][r]) * vw[0][0]
                          + fast_tanh(acc[mq][0][i][1][r]) * vw[0][1]
                          + fast_tanh(acc[mq][1][i][0][r]) * vw[1][0]
                          + fast_tanh(acc[mq][1][i][1][r]) * vw[1][1];
#pragma unroll
                for (int off = 8; off > 0; off >>= 1)
                    val += __shfl_xor(val, off, 64);
                if (ml == 0)
                    atomicAdd(&score[m0 + mq * 128 + (wm << 6) + i * 16 + (q << 2) + r], val);
            }
}

// ---------------- K3: FUSED softmax + weighted sum (compact, bf16) ----------------
__global__ __launch_bounds__(256)
void softmax_wsum(const float* __restrict__ score, const int* __restrict__ cnt,
                  const unsigned short* __restrict__ Ab, float* __restrict__ out) {
    __shared__ float red[8];
    __shared__ float al[2048];
    int b   = blockIdx.x >> 4;
    int seg = blockIdx.x & 15;
    int t   = threadIdx.x;
    int c   = cnt[b];

    float sc[8];
    float mx = -1e30f;
#pragma unroll
    for (int i = 0; i < 8; ++i) {
        int k = i * 256 + t;
        sc[i] = (k < c) ? score[b * 2048 + k] : -1e30f;
        mx = fmaxf(mx, sc[i]);
    }
#pragma unroll
    for (int off = 32; off > 0; off >>= 1)
        mx = fmaxf(mx, __shfl_xor(mx, off, 64));
    if ((t & 63) == 0) red[t >> 6] = mx;
    __syncthreads();
    mx = fmaxf(fmaxf(red[0], red[1]), fmaxf(red[2], red[3]));
    float e[8], sum = 0.f;
#pragma unroll
    for (int i = 0; i < 8; ++i) {
        int k = i * 256 + t;
        e[i] = (k < c) ? __expf(sc[i] - mx) : 0.f;
        sum += e[i];
    }
#pragma unroll
    for (int off = 32; off > 0; off >>= 1)
        sum += __shfl_xor(sum, off, 64);
    if ((t & 63) == 0) red[4 + (t >> 6)] = sum;
    __syncthreads();
    float inv = 1.0f / (red[4] + red[5] + red[6] + red[7]);
#pragma unroll
    for (int i = 0; i < 8; ++i)
        al[i * 256 + t] = e[i] * inv;
    __syncthreads();

    int per = (c + 15) >> 4;
    int s0  = seg * per;
    int s1  = min(s0 + per, c);
    const unsigned short* base = Ab + (size_t)b * 2048 * 1024 + t * 4;
    float a0 = 0.f, a1 = 0.f, a2 = 0.f, a3 = 0.f;
    for (int s = s0; s < s1; ++s) {
        float a = al[s];
        ushort4 h = *(const ushort4*)(base + (size_t)s * 1024);
        a0 = __builtin_fmaf(a, __uint_as_float((unsigned)h.x << 16), a0);
        a1 = __builtin_fmaf(a, __uint_as_float((unsigned)h.y << 16), a1);
        a2 = __builtin_fmaf(a, __uint_as_float((unsigned)h.z << 16), a2);
        a3 = __builtin_fmaf(a, __uint_as_float((unsigned)h.w << 16), a3);
    }
    float* o = out + b * 1024 + t * 4;
    atomicAdd(o + 0, a0);
    atomicAdd(o + 1, a1);
    atomicAdd(o + 2, a2);
    atomicAdd(o + 3, a3);
}

// ================= fallback path (small ws): full-row fp32 pipeline =================
#define LDSS 40
__global__ __launch_bounds__(256)
void score_gemm_f32stage(const float* __restrict__ A, const unsigned short* __restrict__ Bw,
                         const float* __restrict__ v, float* __restrict__ score) {
    const int K = 1024;
    __shared__ __align__(16) unsigned short As[128][LDSS];
    __shared__ __align__(16) unsigned short Bs[128][LDSS];
    const int n0 = (int)blockIdx.x * 128;
    const int m0 = (int)blockIdx.y * 128;
    const int t = threadIdx.x, lane = t & 63, wave = t >> 6;
    const int wm = (wave & 1) * 64, wn = (wave >> 1) * 64;
    const int ml = lane & 15, q = lane >> 4;
    f32x4 acc[4][4];
#pragma unroll
    for (int i = 0; i < 4; ++i)
#pragma unroll
        for (int j = 0; j < 4; ++j) acc[i][j] = (f32x4){0.f,0.f,0.f,0.f};
    const int sr = t >> 3, scc = (t & 7) * 4;
    for (int kk = 0; kk < K; kk += 32) {
#pragma unroll
        for (int p = 0; p < 4; ++p) {
            int r = sr + p * 32;
            float4 va = *(const float4*)&A[(size_t)(m0 + r) * K + kk + scc];
            ushort4 h; h.x = f2bf(va.x); h.y = f2bf(va.y); h.z = f2bf(va.z); h.w = f2bf(va.w);
            *(ushort4*)&As[r][scc] = h;
            ushort4 vb = *(const ushort4*)&Bw[(size_t)(n0 + r) * K + kk + scc];
            *(ushort4*)&Bs[r][scc] = vb;
        }
        __syncthreads();
        bf16x8 af[4], bf[4];
#pragma unroll
        for (int i = 0; i < 4; ++i) af[i] = *(const bf16x8*)&As[wm + i * 16 + ml][q * 8];
#pragma unroll
        for (int j = 0; j < 4; ++j) bf[j] = *(const bf16x8*)&Bs[wn + j * 16 + ml][q * 8];
#pragma unroll
        for (int i = 0; i < 4; ++i)
#pragma unroll
            for (int j = 0; j < 4; ++j)
                acc[i][j] = __builtin_amdgcn_mfma_f32_16x16x32_bf16(af[i], bf[j], acc[i][j], 0, 0, 0);
        __syncthreads();
    }
    float vw[4];
#pragma unroll
    for (int j = 0; j < 4; ++j) vw[j] = v[n0 + wn + j * 16 + ml];
#pragma unroll
    for (int i = 0; i < 4; ++i)
#pragma unroll
        for (int r = 0; r < 4; ++r) {
            float val = 0.f;
#pragma unroll
            for (int j = 0; j < 4; ++j) val += fast_tanh(acc[i][j][r]) * vw[j];
#pragma unroll
            for (int off = 8; off > 0; off >>= 1) val += __shfl_xor(val, off, 64);
            if (ml == 0) atomicAdd(&score[m0 + wm + i * 16 + q * 4 + r], val);
        }
}

__global__ __launch_bounds__(256)
void softmax_kernel(const float* __restrict__ score, const int* __restrict__ mask,
                    float* __restrict__ alpha) {
    const int S = 2048;
    int b = blockIdx.x, t = threadIdx.x;
    __shared__ float red[8];
    float sc[8]; int vd[8];
    float mx = -1e30f;
#pragma unroll
    for (int i = 0; i < 8; ++i) {
        int s = i * 256 + t;
        vd[i] = mask[b * S + s];
        sc[i] = score[b * S + s];
        if (vd[i]) mx = fmaxf(mx, sc[i]);
    }
#pragma unroll
    for (int off = 32; off > 0; off >>= 1)
        mx = fmaxf(mx, __shfl_xor(mx, off, 64));
    if ((t & 63) == 0) red[t >> 6] = mx;
    __syncthreads();
    mx = fmaxf(fmaxf(red[0], red[1]), fmaxf(red[2], red[3]));
    float e[8]; float sum = 0.f;
#pragma unroll
    for (int i = 0; i < 8; ++i) {
        e[i] = vd[i] ? __expf(sc[i] - mx) : 0.f;
        sum += e[i];
    }
#pragma unroll
    for (int off = 32; off > 0; off >>= 1)
        sum += __shfl_xor(sum, off, 64);
    if ((t & 63) == 0) red[4 + (t >> 6)] = sum;
    __syncthreads();
    float inv = 1.0f / (red[4] + red[5] + red[6] + red[7]);
#pragma unroll
    for (int i = 0; i < 8; ++i)
        alpha[b * S + i * 256 + t] = e[i] * inv;
}

__global__ __launch_bounds__(256)
void wsum_kernel(const float* __restrict__ lhs, const float* __restrict__ alpha,
                 float* __restrict__ out) {
    const int S = 2048, E = 1024;
    int b = blockIdx.x >> 6;
    int seg = blockIdx.x & 63;
    int t = threadIdx.x;
    int s0 = seg * 32;
    const float* base = lhs + ((size_t)b * S + s0) * E + t * 4;
    const float* ap = alpha + b * S + s0;
    float4 acc = {0.f, 0.f, 0.f, 0.f};
#pragma unroll 4
    for (int s = 0; s < 32; ++s) {
        float a = ap[s];
        if (a != 0.f) {
            float4 x = *(const float4*)(base + (size_t)s * E);
            acc.x += a * x.x; acc.y += a * x.y; acc.z += a * x.z; acc.w += a * x.w;
        }
    }
    float* o = out + b * E + t * 4;
    atomicAdd(o + 0, acc.x);
    atomicAdd(o + 1, acc.y);
    atomicAdd(o + 2, acc.z);
    atomicAdd(o + 3, acc.w);
}

extern "C" void kernel_launch(void* const* d_in, const int* in_sizes, int n_in,
                              void* d_out, int out_size, void* d_ws, size_t ws_size,
                              hipStream_t stream) {
    const float* lhs  = (const float*)d_in[0];
    const int*   mask = (const int*)d_in[1];
    const float* W    = (const float*)d_in[2];
    const float* Um   = (const float*)d_in[3];
    const float* v    = (const float*)d_in[4];
    float* out = (float*)d_out;

    char* ws = (char*)d_ws;
    unsigned short* wsumrm = (unsigned short*)(ws + 2048u * 1024u);    // 2 MB (row-major)
    float* score           = (float*)(ws + 4096u * 1024u);             // 256 KB
    float* alphac          = (float*)(ws + 4352u * 1024u);             // 256 KB
    unsigned short* ridx   = (unsigned short*)(ws + 4608u * 1024u);    // 128 KB
    int* cnt               = (int*)(ws + 4736u * 1024u);               // 128 B
    unsigned short* Ab     = (unsigned short*)(ws + 5120u * 1024u);    // 128 MB
    const size_t need = 5120ull * 1024ull + 131072ull * 1024ull;

    prep_index<<<1056, 256, 0, stream>>>(W, Um, mask, wsumrm, score, out, ridx, cnt);
    if (ws_size >= need) {
        dim3 gg(512, 32);
        gather_convert<<<gg, 256, 0, stream>>>(lhs, ridx, cnt, Ab);
        score_gemm_v4<<<1024, 512, 0, stream>>>(Ab, wsumrm, v, cnt, score);
        softmax_wsum<<<512, 256, 0, stream>>>(score, cnt, Ab, out);
    } else {
        dim3 g1(8, 512);
        score_gemm_f32stage<<<g1, 256, 0, stream>>>(lhs, wsumrm, v, score);
        softmax_kernel<<<32, 256, 0, stream>>>(score, mask, alphac);
        wsum_kernel<<<2048, 256, 0, stream>>>(lhs, alphac, out);
    }
}

// Round 4
// 485.140 us; speedup vs baseline: 1.0242x; 1.0242x over previous
//
#include <hip/hip_runtime.h>
#include <hip/hip_bf16.h>

// Shapes (fixed): B=32, S=2048, E=1024, U=1024. M = B*S = 65536.
// score[m] = v . tanh( lhs[m,:] @ (W+U)^T )  -- 256x256/BK=64 MFMA GEMM, 4 phases/K-tile
//   keyed by (mq,ksub): each LDS fragment read ONCE per K-tile (24 b128/wave/tile, was 48),
//   B fragments held in regs across the tile. T2 both-sides XOR swizzle; counted vmcnt
//   (4 at p1, 2 at p3 -- never 0 in steady loop); T5 setprio around MFMA clusters.
//   All reads hit buf, all stagings hit bufn -> no same-phase LDS hazards by construction.
// out[b,:] = sum_s softmax(score)[s] * row[s]  -- fused softmax+wsum (compact order)
//
// ws: (2MB unused) | wsumrm bf16 [2MB,4MB) | score [4MB,+256KB) | alphac [+256KB)
//     | ridx u16 [4.5MB,+128KB) | cnt i32 [4.625MB,+128B) | Ab bf16 [5MB,+128MB)

typedef short bf16x8 __attribute__((ext_vector_type(8)));
typedef float f32x4  __attribute__((ext_vector_type(4)));
typedef unsigned short u16x8 __attribute__((ext_vector_type(8)));

static __device__ __forceinline__ unsigned short f2bf(float f) {
    unsigned int x = __float_as_uint(f);
    unsigned int r = x + 0x7FFFu + ((x >> 16) & 1u);   // RNE
    return (unsigned short)(r >> 16);
}

static __device__ __forceinline__ float fast_tanh(float x) {
    float e = __builtin_amdgcn_exp2f(x * 2.885390082f);   // e^{2x}
    float r = __builtin_amdgcn_rcpf(e + 1.0f);
    return __builtin_fmaf(-2.0f, r, 1.0f);
}

// ---------------- K0: [0..1023] wsumrm = bf16(W+U) row-major, zero score/out
//                      [1024..1055] per-batch valid-row index scan ----------------
__global__ __launch_bounds__(256)
void prep_index(const float* __restrict__ W, const float* __restrict__ U,
                const int* __restrict__ mask,
                unsigned short* __restrict__ wsumrm,
                float* __restrict__ score, float* __restrict__ out,
                unsigned short* __restrict__ ridx, int* __restrict__ cnt) {
    __shared__ int sc[256];
    int blk = blockIdx.x, t = threadIdx.x;
    if (blk < 1024) {
        int g = blk * 256 + t;
        int i4 = g * 4;                       // 4 consecutive k of row n
        float4 w = *(const float4*)&W[i4];
        float4 u = *(const float4*)&U[i4];
        ushort4 h;
        h.x = f2bf(w.x + u.x); h.y = f2bf(w.y + u.y);
        h.z = f2bf(w.z + u.z); h.w = f2bf(w.w + u.w);
        *(ushort4*)&wsumrm[i4] = h;           // row-major [n][k]
        if (g < 65536) score[g] = 0.0f;
        if (g < 32768) out[g] = 0.0f;
    } else {
        int b = blk - 1024;
        const int* mrow = mask + b * 2048;
        int m[8], c = 0;
#pragma unroll
        for (int j = 0; j < 8; ++j) { m[j] = mrow[t * 8 + j]; c += (m[j] != 0); }
        sc[t] = c;
        __syncthreads();
        for (int off = 1; off < 256; off <<= 1) {
            int v = (t >= off) ? sc[t - off] : 0;
            __syncthreads();
            sc[t] += v;
            __syncthreads();
        }
        int base = sc[t] - c;
        unsigned short* rb = ridx + b * 2048;
#pragma unroll
        for (int j = 0; j < 8; ++j)
            if (m[j]) rb[base++] = (unsigned short)(t * 8 + j);
        if (t == 255) cnt[b] = sc[255];
    }
}

// ---------------- K1: gather valid rows -> bf16 compact (zero-pad to x256) ----------------
__global__ __launch_bounds__(256)
void gather_convert(const float* __restrict__ lhs, const unsigned short* __restrict__ ridx,
                    const int* __restrict__ cnt, unsigned short* __restrict__ Ab) {
    int b = blockIdx.y;
    int c = cnt[b];
    int cpad = (c + 255) & ~255;
    int r = blockIdx.x * 4 + (threadIdx.x >> 6);
    int lt = threadIdx.x & 63;
    if (r >= cpad) return;
    unsigned short* dst = Ab + ((size_t)b * 2048 + r) * 1024 + lt * 16;
    if (r < c) {
        int s = ridx[b * 2048 + r];
        const float* src = lhs + ((size_t)b * 2048 + s) * 1024 + lt * 16;
        float4 a0 = *(const float4*)(src + 0);
        float4 a1 = *(const float4*)(src + 4);
        float4 a2 = *(const float4*)(src + 8);
        float4 a3 = *(const float4*)(src + 12);
        u16x8 h0, h1;
        h0[0] = f2bf(a0.x); h0[1] = f2bf(a0.y); h0[2] = f2bf(a0.z); h0[3] = f2bf(a0.w);
        h0[4] = f2bf(a1.x); h0[5] = f2bf(a1.y); h0[6] = f2bf(a1.z); h0[7] = f2bf(a1.w);
        h1[0] = f2bf(a2.x); h1[1] = f2bf(a2.y); h1[2] = f2bf(a2.z); h1[3] = f2bf(a2.w);
        h1[4] = f2bf(a3.x); h1[5] = f2bf(a3.y); h1[6] = f2bf(a3.z); h1[7] = f2bf(a3.w);
        *(u16x8*)(dst + 0) = h0;
        *(u16x8*)(dst + 8) = h1;
    } else {
        u16x8 z = (u16x8){0,0,0,0,0,0,0,0};
        *(u16x8*)(dst + 0) = z;
        *(u16x8*)(dst + 8) = z;
    }
}

// ---------------- K2: score GEMM -- 256x256 tile, BK=64, 8 waves (2Mx4N) ---------
// LDS (128 KiB): A[buf][half][128x64 bf16] at buf*16384+half*8192 shorts,
//                B same at +32768 shorts. Half-tile staged = 2 x global_load_lds(16B)/thread.
// Staging slot s=j*512+t covers row lr=s>>3, 16B-slot s&7; SOURCE k-slot pre-swizzled:
//   ks = (s&7) ^ (lr&7)  =>  LDS[lr][slot] = A[lr][slot ^ (lr&7)]  (T2 both-sides).
// Phases keyed (mq,ksub): p0:(A0,k0)+all-B(k0)  p1:(A0,k1)+all-B(k1)  p2:(A1,k0)  p3:(A1,k1)
//   B regs bK[2][2][2] persist across the tile (read once).
// Staging (all to bufn, tile kt+1): p0->A0 p1->B0 p2->B1 p3->A1.
// Waits: p1 vmcnt(4) retires A1(kt) [read at p2]; p3 vmcnt(2) retires A0/B0/B1(kt+1)
//   [read at p0/p1 of kt+1], leaving A1(kt+1) in flight. Never 0 in steady loop.
#define GLD(SRC, LOFF) __builtin_amdgcn_global_load_lds( \
    (const __attribute__((address_space(1))) unsigned int*)(SRC), \
    (__attribute__((address_space(3))) unsigned int*)&L[LOFF], 16, 0, 0)

#define STAGE_A(BUF, MQ, KT) do { \
    GLD(gA[MQ][0] + (KT) * 64, ((BUF) << 14) + ((MQ) << 13) + (wv << 9)); \
    GLD(gA[MQ][1] + (KT) * 64, ((BUF) << 14) + ((MQ) << 13) + 4096 + (wv << 9)); \
} while (0)

#define STAGE_B(BUF, NQ, KT) do { \
    GLD(gB[NQ][0] + (KT) * 64, 32768 + ((BUF) << 14) + ((NQ) << 13) + (wv << 9)); \
    GLD(gB[NQ][1] + (KT) * 64, 32768 + ((BUF) << 14) + ((NQ) << 13) + 4096 + (wv << 9)); \
} while (0)

#define VM4 asm volatile("s_waitcnt vmcnt(4)" ::: "memory");
#define VM2 asm volatile("s_waitcnt vmcnt(2)" ::: "memory");
#define VM0 asm volatile("s_waitcnt vmcnt(0)" ::: "memory");
#define VMNONE
#define NOSTAGE

// Phase tail shared by both variants: stage, wait, barrier, own-read fence, MFMA fence.
#define PHASE_SYNC(STAGES, VMW) \
    __builtin_amdgcn_sched_barrier(0); \
    STAGES \
    VMW \
    __builtin_amdgcn_s_barrier(); \
    asm volatile("s_waitcnt lgkmcnt(0)" ::: "memory"); \
    __builtin_amdgcn_sched_barrier(0);

#define PHASE_END \
    __builtin_amdgcn_s_setprio(0); \
    __builtin_amdgcn_s_barrier(); \
    __builtin_amdgcn_sched_barrier(0);

// mq=0 phase: read A0 frags (4) + ALL B frags of this ksub (4); 16 MFMA on acc[0][*].
#define PHASE0(KS, KOFF, STAGES, VMW) do { \
    bf16x8 af[4]; \
    const int ab_ = (buf << 14) + arow_; \
    const int bb_ = 32768 + (buf << 14) + brow_; \
    _Pragma("unroll") for (int i_ = 0; i_ < 4; ++i_) \
        af[i_] = *(const bf16x8*)&L[ab_ + i_ * 1024 + (KOFF)]; \
    _Pragma("unroll") for (int n_ = 0; n_ < 2; ++n_) \
    _Pragma("unroll") for (int j_ = 0; j_ < 2; ++j_) \
        bK[KS][n_][j_] = *(const bf16x8*)&L[bb_ + (n_ << 13) + j_ * 1024 + (KOFF)]; \
    PHASE_SYNC(STAGES, VMW) \
    __builtin_amdgcn_s_setprio(1); \
    _Pragma("unroll") for (int i_ = 0; i_ < 4; ++i_) \
    _Pragma("unroll") for (int n_ = 0; n_ < 2; ++n_) \
    _Pragma("unroll") for (int j_ = 0; j_ < 2; ++j_) \
        acc[0][n_][i_][j_] = __builtin_amdgcn_mfma_f32_16x16x32_bf16(af[i_], bK[KS][n_][j_], acc[0][n_][i_][j_], 0, 0, 0); \
    PHASE_END \
} while (0)

// mq=1 phase: read A1 frags only (4); B held in bK from p0/p1; 16 MFMA on acc[1][*].
#define PHASE1(KS, KOFF, STAGES, VMW) do { \
    bf16x8 af[4]; \
    const int ab_ = (buf << 14) + 8192 + arow_; \
    _Pragma("unroll") for (int i_ = 0; i_ < 4; ++i_) \
        af[i_] = *(const bf16x8*)&L[ab_ + i_ * 1024 + (KOFF)]; \
    PHASE_SYNC(STAGES, VMW) \
    __builtin_amdgcn_s_setprio(1); \
    _Pragma("unroll") for (int i_ = 0; i_ < 4; ++i_) \
    _Pragma("unroll") for (int n_ = 0; n_ < 2; ++n_) \
    _Pragma("unroll") for (int j_ = 0; j_ < 2; ++j_) \
        acc[1][n_][i_][j_] = __builtin_amdgcn_mfma_f32_16x16x32_bf16(af[i_], bK[KS][n_][j_], acc[1][n_][i_][j_], 0, 0, 0); \
    PHASE_END \
} while (0)

__global__ __launch_bounds__(512, 2)
void score_gemm_v5(const unsigned short* __restrict__ Ab,
                   const unsigned short* __restrict__ Bw,   // wsumrm [1024][1024]
                   const float* __restrict__ v, const int* __restrict__ cnt,
                   float* __restrict__ score) {
    __shared__ __align__(16) unsigned short L[65536];       // 128 KiB

    // bijective XCD swizzle: all 4 n-blocks of an m-tile consecutive on one XCD
    // (A-panel L2 reuse x4; B=2MB L2-resident).
    const int bid = (int)blockIdx.x;
    const int li  = (bid & 7) * 128 + (bid >> 3);
    const int mt  = li >> 2;                  // 0..255 (32 batches x 8 m-tiles)
    const int nI  = li & 3;                   // 0..3
    const int b   = mt >> 3;
    const int lm0 = (mt & 7) << 8;
    const int c   = cnt[b];
    if (lm0 >= ((c + 255) & ~255)) return;
    const int m0  = (b << 11) + lm0;
    const int n0  = nI << 8;

    const int t    = (int)threadIdx.x;
    const int lane = t & 63;
    const int wv   = t >> 6;                  // 0..7
    const int wm   = wv >> 2;                 // 0..1  (M)
    const int wn   = wv & 3;                  // 0..3  (N)
    const int ml   = lane & 15;
    const int q    = lane >> 4;

    // staging source pointers (pre-swizzled k-slot): slot s=j*512+t, lr=s>>3, ks=(t&7)^(lr&7)
    const int lr0 = t >> 3;
    const int ks  = (t & 7) ^ (lr0 & 7);
    const unsigned short* gA[2][2];
    const unsigned short* gB[2][2];
#pragma unroll
    for (int h = 0; h < 2; ++h)
#pragma unroll
        for (int j = 0; j < 2; ++j) {
            gA[h][j] = Ab + (size_t)(m0 + h * 128 + lr0 + j * 64) * 1024 + ks * 8;
            gB[h][j] = Bw + (size_t)(n0 + h * 128 + lr0 + j * 64) * 1024 + ks * 8;
        }

    // ds_read offsets (shorts): row*64 + ((ksub*64 + q*16) ^ ((row&7)<<4))>>1, row&7 == ml&7
    const int xorv  = (ml & 7) << 4;
    const int koff0 = (((q << 4)) ^ xorv) >> 1;
    const int koff1 = ((64 + (q << 4)) ^ xorv) >> 1;
    const int arow_ = ((wm << 6) + ml) * 64;
    const int brow_ = ((wn << 5) + ml) * 64;

    f32x4 acc[2][2][4][2];
#pragma unroll
    for (int x0 = 0; x0 < 2; ++x0)
#pragma unroll
        for (int x1 = 0; x1 < 2; ++x1)
#pragma unroll
            for (int x2 = 0; x2 < 4; ++x2)
#pragma unroll
                for (int x3 = 0; x3 < 2; ++x3)
                    acc[x0][x1][x2][x3] = (f32x4){0.f, 0.f, 0.f, 0.f};

    // prologue: stage all of kt0 into buf0; drain; barrier.
    STAGE_A(0, 0, 0); STAGE_B(0, 0, 0); STAGE_B(0, 1, 0); STAGE_A(0, 1, 0);
    VM0
    __builtin_amdgcn_s_barrier();

    for (int kt = 0; kt < 15; ++kt) {
        const int buf  = kt & 1;
        const int bufn = buf ^ 1;
        bf16x8 bK[2][2][2];                   // all B frags of this tile, read at p0/p1
        PHASE0(0, koff0, STAGE_A(bufn, 0, kt + 1);, VMNONE);
        PHASE0(1, koff1, STAGE_B(bufn, 0, kt + 1);, VM4);   // retire A1(kt) before p2
        PHASE1(0, koff0, STAGE_B(bufn, 1, kt + 1);, VMNONE);
        PHASE1(1, koff1, STAGE_A(bufn, 1, kt + 1);, VM2);   // retire A0/B0/B1(kt+1)
    }
    {   // kt = 15 (buf 1): pure compute; only A1(15) still in flight at entry.
        const int buf = 1;
        bf16x8 bK[2][2][2];
        PHASE0(0, koff0, NOSTAGE;, VMNONE);
        PHASE0(1, koff1, NOSTAGE;, VM0);     // retire A1(15) before p2 reads it
        PHASE1(0, koff0, NOSTAGE;, VMNONE);
        PHASE1(1, koff1, NOSTAGE;, VMNONE);
    }

    // epilogue: score[m] += sum_n v[n]*tanh(P[m,n]).  D layout: col=ml (n), row=q*4+r (m).
    float vw[2][2];
#pragma unroll
    for (int nq = 0; nq < 2; ++nq)
#pragma unroll
        for (int j = 0; j < 2; ++j)
            vw[nq][j] = v[n0 + nq * 128 + (wn << 5) + j * 16 + ml];

#pragma unroll
    for (int mq = 0; mq < 2; ++mq)
#pragma unroll
        for (int i = 0; i < 4; ++i)
#pragma unroll
            for (int r = 0; r < 4; ++r) {
                float val = fast_tanh(acc[mq][0][i][0][r]) * vw[0][0]
                          + fast_tanh(acc[mq][0][i][1][r]) * vw[0][1]
                          + fast_tanh(acc[mq][1][i][0][r]) * vw[1][0]
                          + fast_tanh(acc[mq][1][i][1][r]) * vw[1][1];
#pragma unroll
                for (int off = 8; off > 0; off >>= 1)
                    val += __shfl_xor(val, off, 64);
                if (ml == 0)
                    atomicAdd(&score[m0 + mq * 128 + (wm << 6) + i * 16 + (q << 2) + r], val);
            }
}

// ---------------- K3: FUSED softmax + weighted sum (compact, bf16) ----------------
__global__ __launch_bounds__(256)
void softmax_wsum(const float* __restrict__ score, const int* __restrict__ cnt,
                  const unsigned short* __restrict__ Ab, float* __restrict__ out) {
    __shared__ float red[8];
    __shared__ float al[2048];
    int b   = blockIdx.x >> 4;
    int seg = blockIdx.x & 15;
    int t   = threadIdx.x;
    int c   = cnt[b];

    float sc[8];
    float mx = -1e30f;
#pragma unroll
    for (int i = 0; i < 8; ++i) {
        int k = i * 256 + t;
        sc[i] = (k < c) ? score[b * 2048 + k] : -1e30f;
        mx = fmaxf(mx, sc[i]);
    }
#pragma unroll
    for (int off = 32; off > 0; off >>= 1)
        mx = fmaxf(mx, __shfl_xor(mx, off, 64));
    if ((t & 63) == 0) red[t >> 6] = mx;
    __syncthreads();
    mx = fmaxf(fmaxf(red[0], red[1]), fmaxf(red[2], red[3]));
    float e[8], sum = 0.f;
#pragma unroll
    for (int i = 0; i < 8; ++i) {
        int k = i * 256 + t;
        e[i] = (k < c) ? __expf(sc[i] - mx) : 0.f;
        sum += e[i];
    }
#pragma unroll
    for (int off = 32; off > 0; off >>= 1)
        sum += __shfl_xor(sum, off, 64);
    if ((t & 63) == 0) red[4 + (t >> 6)] = sum;
    __syncthreads();
    float inv = 1.0f / (red[4] + red[5] + red[6] + red[7]);
#pragma unroll
    for (int i = 0; i < 8; ++i)
        al[i * 256 + t] = e[i] * inv;
    __syncthreads();

    int per = (c + 15) >> 4;
    int s0  = seg * per;
    int s1  = min(s0 + per, c);
    const unsigned short* base = Ab + (size_t)b * 2048 * 1024 + t * 4;
    float a0 = 0.f, a1 = 0.f, a2 = 0.f, a3 = 0.f;
    for (int s = s0; s < s1; ++s) {
        float a = al[s];
        ushort4 h = *(const ushort4*)(base + (size_t)s * 1024);
        a0 = __builtin_fmaf(a, __uint_as_float((unsigned)h.x << 16), a0);
        a1 = __builtin_fmaf(a, __uint_as_float((unsigned)h.y << 16), a1);
        a2 = __builtin_fmaf(a, __uint_as_float((unsigned)h.z << 16), a2);
        a3 = __builtin_fmaf(a, __uint_as_float((unsigned)h.w << 16), a3);
    }
    float* o = out + b * 1024 + t * 4;
    atomicAdd(o + 0, a0);
    atomicAdd(o + 1, a1);
    atomicAdd(o + 2, a2);
    atomicAdd(o + 3, a3);
}

// ================= fallback path (small ws): full-row fp32 pipeline =================
#define LDSS 40
__global__ __launch_bounds__(256)
void score_gemm_f32stage(const float* __restrict__ A, const unsigned short* __restrict__ Bw,
                         const float* __restrict__ v, float* __restrict__ score) {
    const int K = 1024;
    __shared__ __align__(16) unsigned short As[128][LDSS];
    __shared__ __align__(16) unsigned short Bs[128][LDSS];
    const int n0 = (int)blockIdx.x * 128;
    const int m0 = (int)blockIdx.y * 128;
    const int t = threadIdx.x, lane = t & 63, wave = t >> 6;
    const int wm = (wave & 1) * 64, wn = (wave >> 1) * 64;
    const int ml = lane & 15, q = lane >> 4;
    f32x4 acc[4][4];
#pragma unroll
    for (int i = 0; i < 4; ++i)
#pragma unroll
        for (int j = 0; j < 4; ++j) acc[i][j] = (f32x4){0.f,0.f,0.f,0.f};
    const int sr = t >> 3, scc = (t & 7) * 4;
    for (int kk = 0; kk < K; kk += 32) {
#pragma unroll
        for (int p = 0; p < 4; ++p) {
            int r = sr + p * 32;
            float4 va = *(const float4*)&A[(size_t)(m0 + r) * K + kk + scc];
            ushort4 h; h.x = f2bf(va.x); h.y = f2bf(va.y); h.z = f2bf(va.z); h.w = f2bf(va.w);
            *(ushort4*)&As[r][scc] = h;
            ushort4 vb = *(const ushort4*)&Bw[(size_t)(n0 + r) * K + kk + scc];
            *(ushort4*)&Bs[r][scc] = vb;
        }
        __syncthreads();
        bf16x8 af[4], bf[4];
#pragma unroll
        for (int i = 0; i < 4; ++i) af[i] = *(const bf16x8*)&As[wm + i * 16 + ml][q * 8];
#pragma unroll
        for (int j = 0; j < 4; ++j) bf[j] = *(const bf16x8*)&Bs[wn + j * 16 + ml][q * 8];
#pragma unroll
        for (int i = 0; i < 4; ++i)
#pragma unroll
            for (int j = 0; j < 4; ++j)
                acc[i][j] = __builtin_amdgcn_mfma_f32_16x16x32_bf16(af[i], bf[j], acc[i][j], 0, 0, 0);
        __syncthreads();
    }
    float vw[4];
#pragma unroll
    for (int j = 0; j < 4; ++j) vw[j] = v[n0 + wn + j * 16 + ml];
#pragma unroll
    for (int i = 0; i < 4; ++i)
#pragma unroll
        for (int r = 0; r < 4; ++r) {
            float val = 0.f;
#pragma unroll
            for (int j = 0; j < 4; ++j) val += fast_tanh(acc[i][j][r]) * vw[j];
#pragma unroll
            for (int off = 8; off > 0; off >>= 1) val += __shfl_xor(val, off, 64);
            if (ml == 0) atomicAdd(&score[m0 + wm + i * 16 + q * 4 + r], val);
        }
}

__global__ __launch_bounds__(256)
void softmax_kernel(const float* __restrict__ score, const int* __restrict__ mask,
                    float* __restrict__ alpha) {
    const int S = 2048;
    int b = blockIdx.x, t = threadIdx.x;
    __shared__ float red[8];
    float sc[8]; int vd[8];
    float mx = -1e30f;
#pragma unroll
    for (int i = 0; i < 8; ++i) {
        int s = i * 256 + t;
        vd[i] = mask[b * S + s];
        sc[i] = score[b * S + s];
        if (vd[i]) mx = fmaxf(mx, sc[i]);
    }
#pragma unroll
    for (int off = 32; off > 0; off >>= 1)
        mx = fmaxf(mx, __shfl_xor(mx, off, 64));
    if ((t & 63) == 0) red[t >> 6] = mx;
    __syncthreads();
    mx = fmaxf(fmaxf(red[0], red[1]), fmaxf(red[2], red[3]));
    float e[8]; float sum = 0.f;
#pragma unroll
    for (int i = 0; i < 8; ++i) {
        e[i] = vd[i] ? __expf(sc[i] - mx) : 0.f;
        sum += e[i];
    }
#pragma unroll
    for (int off = 32; off > 0; off >>= 1)
        sum += __shfl_xor(sum, off, 64);
    if ((t & 63) == 0) red[4 + (t >> 6)] = sum;
    __syncthreads();
    float inv = 1.0f / (red[4] + red[5] + red[6] + red[7]);
#pragma unroll
    for (int i = 0; i < 8; ++i)
        alpha[b * S + i * 256 + t] = e[i] * inv;
}

__global__ __launch_bounds__(256)
void wsum_kernel(const float* __restrict__ lhs, const float* __restrict__ alpha,
                 float* __restrict__ out) {
    const int S = 2048, E = 1024;
    int b = blockIdx.x >> 6;
    int seg = blockIdx.x & 63;
    int t = threadIdx.x;
    int s0 = seg * 32;
    const float* base = lhs + ((size_t)b * S + s0) * E + t * 4;
    const float* ap = alpha + b * S + s0;
    float4 acc = {0.f, 0.f, 0.f, 0.f};
#pragma unroll 4
    for (int s = 0; s < 32; ++s) {
        float a = ap[s];
        if (a != 0.f) {
            float4 x = *(const float4*)(base + (size_t)s * E);
            acc.x += a * x.x; acc.y += a * x.y; acc.z += a * x.z; acc.w += a * x.w;
        }
    }
    float* o = out + b * E + t * 4;
    atomicAdd(o + 0, acc.x);
    atomicAdd(o + 1, acc.y);
    atomicAdd(o + 2, acc.z);
    atomicAdd(o + 3, acc.w);
}

extern "C" void kernel_launch(void* const* d_in, const int* in_sizes, int n_in,
                              void* d_out, int out_size, void* d_ws, size_t ws_size,
                              hipStream_t stream) {
    const float* lhs  = (const float*)d_in[0];
    const int*   mask = (const int*)d_in[1];
    const float* W    = (const float*)d_in[2];
    const float* Um   = (const float*)d_in[3];
    const float* v    = (const float*)d_in[4];
    float* out = (float*)d_out;

    char* ws = (char*)d_ws;
    unsigned short* wsumrm = (unsigned short*)(ws + 2048u * 1024u);    // 2 MB (row-major)
    float* score           = (float*)(ws + 4096u * 1024u);             // 256 KB
    float* alphac          = (float*)(ws + 4352u * 1024u);             // 256 KB
    unsigned short* ridx   = (unsigned short*)(ws + 4608u * 1024u);    // 128 KB
    int* cnt               = (int*)(ws + 4736u * 1024u);               // 128 B
    unsigned short* Ab     = (unsigned short*)(ws + 5120u * 1024u);    // 128 MB
    const size_t need = 5120ull * 1024ull + 131072ull * 1024ull;

    prep_index<<<1056, 256, 0, stream>>>(W, Um, mask, wsumrm, score, out, ridx, cnt);
    if (ws_size >= need) {
        dim3 gg(512, 32);
        gather_convert<<<gg, 256, 0, stream>>>(lhs, ridx, cnt, Ab);
        score_gemm_v5<<<1024, 512, 0, stream>>>(Ab, wsumrm, v, cnt, score);
        softmax_wsum<<<512, 256, 0, stream>>>(score, cnt, Ab, out);
    } else {
        dim3 g1(8, 512);
        score_gemm_f32stage<<<g1, 256, 0, stream>>>(lhs, wsumrm, v, score);
        softmax_kernel<<<32, 256, 0, stream>>>(score, mask, alphac);
        wsum_kernel<<<2048, 256, 0, stream>>>(lhs, alphac, out);
    }
}